// Round 1
// baseline (203.890 us; speedup 1.0000x reference)
//
#include <hip/hip_runtime.h>
#include <hip/hip_fp16.h>
#include <math.h>

#define NX   160
#define N2   25600        // 160*160
#define N3   4096000      // 160^3
#define NB   4

#define ZPB  2            // z-planes per conv_xy block (R5: 4->2, halve LDS -> 8 blk/CU)
#define NBLK_XY 8000      // 5*5 tiles * 80 z-groups * 4 b
#define BLKS_PER_B 2000   // 25 * 80

#define ZCH  10           // z-chunk per conv_z thread (R5: 20->10, grid 800->1600)
#define NBLK_Z 1600       // 40 x4 * 160 y * 16 zc * 4 b / 256

#define SB_W 36           // 32 cols + 4 pad floats (16B-aligned rows)
#define SB_PLANE (40 * SB_W)

// 1D Gaussian taps exp(-d^2/50), d=-4..4 (NOT normalized, matches reference)
__device__ __constant__ float G1[9] = {
    0.72614903f, 0.83527021f, 0.92311635f, 0.98019867f, 1.0f,
    0.98019867f, 0.92311635f, 0.83527021f, 0.72614903f};

// edge sums: FULL - missing taps at low/high boundary
#define ES_FULL 7.92946852f
__device__ __constant__ float ES_M[4] = {3.46473426f, 2.48453559f, 1.56141924f,
                                         0.72614903f};
__device__ inline float edge_sum(int i) {
    float s = ES_FULL;
    if (i < 4) s -= ES_M[i];
    if (i > NX - 5) s -= ES_M[NX - 1 - i];
    return s;
}

__device__ inline float4 f4_zero() { return make_float4(0.f, 0.f, 0.f, 0.f); }
__device__ inline float4 f4_axpy(float a, float4 b, float4 c) {
    return make_float4(c.x + a * b.x, c.y + a * b.y, c.z + a * b.z, c.w + a * b.w);
}

__device__ inline float4 load_t4(const __half* p) {
    uint2 u = *(const uint2*)p;
    __half2 a = *(const __half2*)&u.x;
    __half2 b = *(const __half2*)&u.y;
    float2 fa = __half22float2(a);
    float2 fb = __half22float2(b);
    return make_float4(fa.x, fa.y, fb.x, fb.y);
}

// block = 256 threads (4 waves). Reduce NV doubles, plain store (NO atomics,
// NO fences — R4 showed per-block __threadfence+ticket costs ~600us).
template <int NV>
__device__ inline void block_reduce_store(double* vals, double* dst) {
    __shared__ double red[4][NV];
    int lane = threadIdx.x & 63;
    int wave = threadIdx.x >> 6;
#pragma unroll
    for (int v = 0; v < NV; ++v) {
        double x = vals[v];
#pragma unroll
        for (int off = 32; off > 0; off >>= 1) x += __shfl_down(x, off, 64);
        if (lane == 0) red[wave][v] = x;
    }
    __syncthreads();
    if (threadIdx.x < NV) {
        int v = threadIdx.x;
        dst[v] = red[0][v] + red[1][v] + red[2][v] + red[3][v];
    }
}

// Separable x+y conv of labels for ZPB z-planes per block.
// x-conv reads labels straight from global (L1 absorbs the 3x float4 overlap),
// y-conv via sB LDS, t stored as fp16. Fused per-batch partial sums -> pS.
// R5: ZPB=2 -> LDS 11.6KB -> 8 blocks/CU (wave-capped), was 6 at 23.5KB.
__global__ __launch_bounds__(256) void conv_xy_kernel(
    const float* __restrict__ labels, const float* __restrict__ inputs,
    __half* __restrict__ t, double* __restrict__ pS) {
    __shared__ float sB[ZPB * SB_PLANE];

    int bid = blockIdx.x;
    int tileX = bid % 5;
    int tileY = (bid / 5) % 5;
    int zq = (bid / 25) % 80;
    int b = bid / BLKS_PER_B;
    int zbase = zq * ZPB;
    int x0 = tileX * 32, y0 = tileY * 32;
    int tid = threadIdx.x;
    int baseOff = b * N3 + zbase * N2;

    // phase 1: x-conv, ZPB planes x 40 rows x 8 float4 outputs (640 = 2.5*256)
    for (int i = tid; i < ZPB * 320; i += 256) {
        int j = i / 320;
        int rem = i - 320 * j;
        int r = rem >> 3, x4 = rem & 7;
        int gy = y0 + r - 4;
        int gxf = x0 + 4 * x4 - 4;   // window start (multiple of 4)
        float w[12];
        if (gy >= 0 && gy < NX) {
            const float* row = &labels[baseOff + j * N2 + gy * NX];
#pragma unroll
            for (int c = 0; c < 3; ++c) {
                int gx = gxf + 4 * c;
                float4 v = (gx >= 0 && gx <= NX - 4) ? *(const float4*)&row[gx]
                                                     : f4_zero();
                w[4 * c] = v.x; w[4 * c + 1] = v.y;
                w[4 * c + 2] = v.z; w[4 * c + 3] = v.w;
            }
        } else {
#pragma unroll
            for (int c = 0; c < 12; ++c) w[c] = 0.f;
        }
        float4 o = f4_zero();
#pragma unroll
        for (int d = 0; d < 9; ++d) {
            float g = G1[d];
            o.x += g * w[d];
            o.y += g * w[d + 1];
            o.z += g * w[d + 2];
            o.w += g * w[d + 3];
        }
        *(float4*)&sB[j * SB_PLANE + r * SB_W + 4 * x4] = o;
    }
    __syncthreads();

    // phase 2: y-conv (ZPB float4 per thread) + fp16 store + fused sums
    int oy = tid >> 3, x4 = tid & 7;
    double sp = 0.0, sip = 0.0, si = 0.0;
#pragma unroll
    for (int j = 0; j < ZPB; ++j) {
        float4 acc = f4_zero();
#pragma unroll
        for (int d = 0; d < 9; ++d) {
            float4 v = *(const float4*)&sB[j * SB_PLANE + (oy + d) * SB_W + 4 * x4];
            acc = f4_axpy(G1[d], v, acc);
        }
        int gi = baseOff + j * N2 + (y0 + oy) * NX + (x0 + 4 * x4);
        __half2 ha = __floats2half2_rn(acc.x, acc.y);
        __half2 hb = __floats2half2_rn(acc.z, acc.w);
        uint2 u;
        u.x = *(unsigned int*)&ha;
        u.y = *(unsigned int*)&hb;
        *(uint2*)&t[gi] = u;   // byte addr 2*gi, gi%4==0 -> 8B aligned

        float4 p = *(const float4*)&labels[gi];
        float4 in = *(const float4*)&inputs[gi];
        sp += (double)(p.x + p.y + p.z + p.w);
        sip += (double)(in.x * p.x + in.y * p.y + in.z * p.z + in.w * p.w);
        si += (double)(in.x + in.y + in.z + in.w);
    }
    double vals[3] = {sp, sip, si};
    block_reduce_store<3>(vals, pS + 3 * bid);
}

// one block per batch: sum 2000 per-block partials -> S[3b+v]
__global__ __launch_bounds__(256) void reduce_S_kernel(
    const double* __restrict__ pS, double* __restrict__ S) {
    int b = blockIdx.x;
    double v0 = 0, v1 = 0, v2 = 0;
    for (int i = threadIdx.x; i < BLKS_PER_B; i += 256) {
        const double* p = pS + 3 * (b * BLKS_PER_B + i);
        v0 += p[0]; v1 += p[1]; v2 += p[2];
    }
    double vals[3] = {v0, v1, v2};
    block_reduce_store<3>(vals, S + 3 * b);
}

// z-conv via register sliding window (float4 = 4 x-cols), t in fp16.
// R5: z-chunk 20->10 (grid 800->1600 blocks, fixes the 12.5-waves/CU grid cap),
// load batches of 2 z-steps (6 float4 in flight, keeps VGPR ~90 -> ~20 waves/CU).
// Per-block partials -> pZ (plain store).
__global__ __launch_bounds__(256) void conv_z_kernel(
    const __half* __restrict__ t, const float* __restrict__ labels,
    const float* __restrict__ inputs, const double* __restrict__ S,
    double* __restrict__ pZ) {
    int tid = threadIdx.x;
    int tidg = blockIdx.x * 256 + tid;  // 0 .. 409599
    int x4 = tidg % 40;           // float4 column; x = 4*x4
    int r = tidg / 40;
    int y = r % NX;
    r /= NX;
    int zc = r % 16;              // z chunk of ZCH=10
    int b = r / 16;

    // per-batch means (class 0: p, class 1: 1-p)
    double sp = S[3 * b + 0], sip = S[3 * b + 1], si = S[3 * b + 2];
    const double Nv = (double)N3;
    float m0 = (float)((sip / Nv) / (sp / Nv + 1e-5));
    float m1 = (float)(((si - sip) / Nv) / ((Nv - sp) / Nv + 1e-5));

    int x = x4 * 4;
    float ey = edge_sum(y);
    float cx[4] = {edge_sum(x) * ey, edge_sum(x + 1) * ey,
                   edge_sum(x + 2) * ey, edge_sum(x + 3) * ey};

    int z0 = zc * ZCH;
    int base = b * N3 + y * NX + x;

    float4 win[9];
#pragma unroll
    for (int d = 0; d < 9; ++d) {
        int z = z0 - 4 + d;
        win[d] = (z >= 0 && z < NX) ? load_t4(&t[base + z * N2]) : f4_zero();
    }

    float n0 = 0.f, d0 = 0.f, n1 = 0.f, d1 = 0.f;
    for (int zb = 0; zb < 5; ++zb) {
        int z = z0 + 2 * zb;
        float4 tn[2], pv[2], iv[2];
#pragma unroll
        for (int j = 0; j < 2; ++j) {
            int zl = z + j + 5;
            tn[j] = (zl < NX) ? load_t4(&t[base + zl * N2]) : f4_zero();
            int gi = base + (z + j) * N2;
            pv[j] = *(const float4*)&labels[gi];
            iv[j] = *(const float4*)&inputs[gi];
        }
#pragma unroll
        for (int j = 0; j < 2; ++j) {
            float4 c4 = f4_zero();
#pragma unroll
            for (int d = 0; d < 9; ++d) c4 = f4_axpy(G1[d], win[d], c4);
            float ez = edge_sum(z + j);
            float pc[4] = {pv[j].x, pv[j].y, pv[j].z, pv[j].w};
            float ic[4] = {iv[j].x, iv[j].y, iv[j].z, iv[j].w};
            float cc[4] = {c4.x, c4.y, c4.z, c4.w};
#pragma unroll
            for (int l = 0; l < 4; ++l) {
                float c1 = cx[l] * ez - cc[l];  // conv(1-p) via conv(ones)
                float df0 = ic[l] - m0; df0 *= df0;
                float w0 = __expf(-df0 * df0);
                float df1 = ic[l] - m1; df1 *= df1;
                float w1 = __expf(-df1 * df1);
                n0 += cc[l] * pc[l] * w0;
                d0 += cc[l] * w0;
                n1 += c1 * (1.f - pc[l]) * w1;
                d1 += c1 * w1;
            }
#pragma unroll
            for (int d = 0; d < 8; ++d) win[d] = win[d + 1];
            win[8] = tn[j];
        }
    }
    double vals[4] = {(double)n0, (double)d0, (double)n1, (double)d1};
    block_reduce_store<4>(vals, pZ + 4 * blockIdx.x);
}

// single block: sum 1600 per-block partials, compute final loss
__global__ __launch_bounds__(256) void finalize_kernel(
    const double* __restrict__ pZ, float* __restrict__ out) {
    double a0 = 0, a1 = 0, a2 = 0, a3 = 0;
    for (int i = threadIdx.x; i < NBLK_Z; i += 256) {
        const double* p = &pZ[4 * i];
        a0 += p[0]; a1 += p[1]; a2 += p[2]; a3 += p[3];
    }
    __shared__ double red[4][4];
    int lane = threadIdx.x & 63;
    int wave = threadIdx.x >> 6;
    double vals[4] = {a0, a1, a2, a3};
#pragma unroll
    for (int v = 0; v < 4; ++v) {
        double x = vals[v];
#pragma unroll
        for (int off = 32; off > 0; off >>= 1) x += __shfl_down(x, off, 64);
        if (lane == 0) red[wave][v] = x;
    }
    __syncthreads();
    if (threadIdx.x == 0) {
        double acc[4];
#pragma unroll
        for (int v = 0; v < 4; ++v)
            acc[v] = red[0][v] + red[1][v] + red[2][v] + red[3][v];
        double r0 = fabs(acc[0] / (acc[1] + 1e-6));
        double r1 = fabs(acc[2] / (acc[3] + 1e-6));
        out[0] = (float)(2.0 - r0 - r1);
    }
}

extern "C" void kernel_launch(void* const* d_in, const int* in_sizes, int n_in,
                              void* d_out, int out_size, void* d_ws, size_t ws_size,
                              hipStream_t stream) {
    const float* labels = (const float*)d_in[0];
    const float* inputs = (const float*)d_in[1];
    float* out = (float*)d_out;

    // ws layout:
    //   [0)       pS : 8000*3 doubles = 192000 B
    //   [192000)  S  : 12 doubles (96 B)
    //   [192128)  pZ : 1600*4 doubles = 51200 B  (ends 243328)
    //   [524288)  t  : 4*160^3 halves = 32,768,000 B
    double* pS = (double*)d_ws;
    double* S  = (double*)((char*)d_ws + 192000);
    double* pZ = (double*)((char*)d_ws + 192128);
    __half* t  = (__half*)((char*)d_ws + 524288);

    hipLaunchKernelGGL(conv_xy_kernel, dim3(NBLK_XY), dim3(256), 0, stream,
                       labels, inputs, t, pS);
    hipLaunchKernelGGL(reduce_S_kernel, dim3(NB), dim3(256), 0, stream, pS, S);
    hipLaunchKernelGGL(conv_z_kernel, dim3(NBLK_Z), dim3(256), 0, stream,
                       t, labels, inputs, S, pZ);
    hipLaunchKernelGGL(finalize_kernel, dim3(1), dim3(256), 0, stream, pZ, out);
}

// Round 2
// 202.164 us; speedup vs baseline: 1.0085x; 1.0085x over previous
//
#include <hip/hip_runtime.h>
#include <hip/hip_fp16.h>
#include <math.h>

#define NX   160
#define N2   25600        // 160*160
#define N3   4096000      // 160^3
#define NB   4

#define ZPB  2            // z-planes per conv_xy block (R5: LDS 11.6KB -> 8 blk/CU)
#define NBLK_XY 8000      // 5*5 tiles * 80 z-groups * 4 b
#define BLKS_PER_B 2000   // 25 * 80

#define ZCH  10           // z-chunk per conv_z thread
#define NBLK_Z 1600       // 40 x4 * 160 y * 16 zc * 4 b / 256

#define SB_W 36           // 32 cols + 4 pad floats (16B-aligned rows)
#define SB_PLANE (40 * SB_W)

// R6: XCD-chunked bijective swizzle (T1). HW-consecutive blocks round-robin
// XCDs; remap so each XCD owns a CONTIGUOUS logical range -> tile/z halos
// shared by logical neighbors become same-XCD L2 hits. Valid: N%8==0.
__device__ inline int xcd_swz(int bid, int nblk) {
    return (bid & 7) * (nblk >> 3) + (bid >> 3);
}

// 1D Gaussian taps exp(-d^2/50), d=-4..4 (NOT normalized, matches reference)
__device__ __constant__ float G1[9] = {
    0.72614903f, 0.83527021f, 0.92311635f, 0.98019867f, 1.0f,
    0.98019867f, 0.92311635f, 0.83527021f, 0.72614903f};

// edge sums: FULL - missing taps at low/high boundary
#define ES_FULL 7.92946852f
__device__ __constant__ float ES_M[4] = {3.46473426f, 2.48453559f, 1.56141924f,
                                         0.72614903f};
__device__ inline float edge_sum(int i) {
    float s = ES_FULL;
    if (i < 4) s -= ES_M[i];
    if (i > NX - 5) s -= ES_M[NX - 1 - i];
    return s;
}

__device__ inline float4 f4_zero() { return make_float4(0.f, 0.f, 0.f, 0.f); }
__device__ inline float4 f4_axpy(float a, float4 b, float4 c) {
    return make_float4(c.x + a * b.x, c.y + a * b.y, c.z + a * b.z, c.w + a * b.w);
}

__device__ inline float4 load_t4(const __half* p) {
    uint2 u = *(const uint2*)p;
    __half2 a = *(const __half2*)&u.x;
    __half2 b = *(const __half2*)&u.y;
    float2 fa = __half22float2(a);
    float2 fb = __half22float2(b);
    return make_float4(fa.x, fa.y, fb.x, fb.y);
}

// block = 256 threads (4 waves). Reduce NV doubles, plain store (NO atomics,
// NO fences — R4 showed per-block __threadfence+ticket costs ~600us).
template <int NV>
__device__ inline void block_reduce_store(double* vals, double* dst) {
    __shared__ double red[4][NV];
    int lane = threadIdx.x & 63;
    int wave = threadIdx.x >> 6;
#pragma unroll
    for (int v = 0; v < NV; ++v) {
        double x = vals[v];
#pragma unroll
        for (int off = 32; off > 0; off >>= 1) x += __shfl_down(x, off, 64);
        if (lane == 0) red[wave][v] = x;
    }
    __syncthreads();
    if (threadIdx.x < NV) {
        int v = threadIdx.x;
        dst[v] = red[0][v] + red[1][v] + red[2][v] + red[3][v];
    }
}

// Separable x+y conv of labels for ZPB z-planes per block.
// x-conv reads labels straight from global (L1 absorbs the 3x float4 overlap),
// y-conv via sB LDS, t stored as fp16. Fused per-batch partial sums -> pS.
__global__ __launch_bounds__(256) void conv_xy_kernel(
    const float* __restrict__ labels, const float* __restrict__ inputs,
    __half* __restrict__ t, double* __restrict__ pS) {
    __shared__ float sB[ZPB * SB_PLANE];

    int bid = xcd_swz(blockIdx.x, NBLK_XY);   // R6: XCD-chunked logical id
    int tileX = bid % 5;
    int tileY = (bid / 5) % 5;
    int zq = (bid / 25) % 80;
    int b = bid / BLKS_PER_B;
    int zbase = zq * ZPB;
    int x0 = tileX * 32, y0 = tileY * 32;
    int tid = threadIdx.x;
    int baseOff = b * N3 + zbase * N2;

    // phase 1: x-conv, ZPB planes x 40 rows x 8 float4 outputs (640 = 2.5*256)
    for (int i = tid; i < ZPB * 320; i += 256) {
        int j = i / 320;
        int rem = i - 320 * j;
        int r = rem >> 3, x4 = rem & 7;
        int gy = y0 + r - 4;
        int gxf = x0 + 4 * x4 - 4;   // window start (multiple of 4)
        float w[12];
        if (gy >= 0 && gy < NX) {
            const float* row = &labels[baseOff + j * N2 + gy * NX];
#pragma unroll
            for (int c = 0; c < 3; ++c) {
                int gx = gxf + 4 * c;
                float4 v = (gx >= 0 && gx <= NX - 4) ? *(const float4*)&row[gx]
                                                     : f4_zero();
                w[4 * c] = v.x; w[4 * c + 1] = v.y;
                w[4 * c + 2] = v.z; w[4 * c + 3] = v.w;
            }
        } else {
#pragma unroll
            for (int c = 0; c < 12; ++c) w[c] = 0.f;
        }
        float4 o = f4_zero();
#pragma unroll
        for (int d = 0; d < 9; ++d) {
            float g = G1[d];
            o.x += g * w[d];
            o.y += g * w[d + 1];
            o.z += g * w[d + 2];
            o.w += g * w[d + 3];
        }
        *(float4*)&sB[j * SB_PLANE + r * SB_W + 4 * x4] = o;
    }
    __syncthreads();

    // phase 2: y-conv (ZPB float4 per thread) + fp16 store + fused sums
    int oy = tid >> 3, x4 = tid & 7;
    double sp = 0.0, sip = 0.0, si = 0.0;
#pragma unroll
    for (int j = 0; j < ZPB; ++j) {
        float4 acc = f4_zero();
#pragma unroll
        for (int d = 0; d < 9; ++d) {
            float4 v = *(const float4*)&sB[j * SB_PLANE + (oy + d) * SB_W + 4 * x4];
            acc = f4_axpy(G1[d], v, acc);
        }
        int gi = baseOff + j * N2 + (y0 + oy) * NX + (x0 + 4 * x4);
        __half2 ha = __floats2half2_rn(acc.x, acc.y);
        __half2 hb = __floats2half2_rn(acc.z, acc.w);
        uint2 u;
        u.x = *(unsigned int*)&ha;
        u.y = *(unsigned int*)&hb;
        *(uint2*)&t[gi] = u;   // byte addr 2*gi, gi%4==0 -> 8B aligned

        float4 p = *(const float4*)&labels[gi];
        float4 in = *(const float4*)&inputs[gi];
        sp += (double)(p.x + p.y + p.z + p.w);
        sip += (double)(in.x * p.x + in.y * p.y + in.z * p.z + in.w * p.w);
        si += (double)(in.x + in.y + in.z + in.w);
    }
    double vals[3] = {sp, sip, si};
    block_reduce_store<3>(vals, pS + 3 * bid);
}

// z-conv via register sliding window (float4 = 4 x-cols), t in fp16.
// R6: reduce_S folded in — every block redundantly reduces ITS batch's 2000x3
// pS partials (L2-resident, same summation order as the old reduce_S_kernel
// -> bitwise-identical m0/m1), removing one dispatch + its 252-idle-CU bubble.
__global__ __launch_bounds__(256) void conv_z_kernel(
    const __half* __restrict__ t, const float* __restrict__ labels,
    const float* __restrict__ inputs, const double* __restrict__ pS,
    double* __restrict__ pZ) {
    int tid = threadIdx.x;
    int lbid = xcd_swz(blockIdx.x, NBLK_Z);   // R6: XCD-chunked logical id
    int tidg = lbid * 256 + tid;  // 0 .. 409599
    int x4 = tidg % 40;           // float4 column; x = 4*x4
    int r = tidg / 40;
    int y = r % NX;
    r /= NX;
    int zc = r % 16;              // z chunk of ZCH=10
    int b = r / 16;               // uniform per block (400 blocks per batch)

    // ---- fused S reduce (replaces reduce_S_kernel) ----
    __shared__ float sM[2];
    {
        double v0 = 0, v1 = 0, v2 = 0;
        for (int i = tid; i < BLKS_PER_B; i += 256) {
            const double* p = pS + 3 * (b * BLKS_PER_B + i);
            v0 += p[0]; v1 += p[1]; v2 += p[2];
        }
        __shared__ double red[4][3];
        int lane = tid & 63, wave = tid >> 6;
        double vals[3] = {v0, v1, v2};
#pragma unroll
        for (int v = 0; v < 3; ++v) {
            double x = vals[v];
#pragma unroll
            for (int off = 32; off > 0; off >>= 1) x += __shfl_down(x, off, 64);
            if (lane == 0) red[wave][v] = x;
        }
        __syncthreads();
        if (tid == 0) {
            double sp = red[0][0] + red[1][0] + red[2][0] + red[3][0];
            double sip = red[0][1] + red[1][1] + red[2][1] + red[3][1];
            double si = red[0][2] + red[1][2] + red[2][2] + red[3][2];
            const double Nv = (double)N3;
            sM[0] = (float)((sip / Nv) / (sp / Nv + 1e-5));
            sM[1] = (float)(((si - sip) / Nv) / ((Nv - sp) / Nv + 1e-5));
        }
        __syncthreads();
    }
    float m0 = sM[0], m1 = sM[1];

    int x = x4 * 4;
    float ey = edge_sum(y);
    float cx[4] = {edge_sum(x) * ey, edge_sum(x + 1) * ey,
                   edge_sum(x + 2) * ey, edge_sum(x + 3) * ey};

    int z0 = zc * ZCH;
    int base = b * N3 + y * NX + x;

    float4 win[9];
#pragma unroll
    for (int d = 0; d < 9; ++d) {
        int z = z0 - 4 + d;
        win[d] = (z >= 0 && z < NX) ? load_t4(&t[base + z * N2]) : f4_zero();
    }

    float n0 = 0.f, d0 = 0.f, n1 = 0.f, d1 = 0.f;
    for (int zb = 0; zb < 5; ++zb) {
        int z = z0 + 2 * zb;
        float4 tn[2], pv[2], iv[2];
#pragma unroll
        for (int j = 0; j < 2; ++j) {
            int zl = z + j + 5;
            tn[j] = (zl < NX) ? load_t4(&t[base + zl * N2]) : f4_zero();
            int gi = base + (z + j) * N2;
            pv[j] = *(const float4*)&labels[gi];
            iv[j] = *(const float4*)&inputs[gi];
        }
#pragma unroll
        for (int j = 0; j < 2; ++j) {
            float4 c4 = f4_zero();
#pragma unroll
            for (int d = 0; d < 9; ++d) c4 = f4_axpy(G1[d], win[d], c4);
            float ez = edge_sum(z + j);
            float pc[4] = {pv[j].x, pv[j].y, pv[j].z, pv[j].w};
            float ic[4] = {iv[j].x, iv[j].y, iv[j].z, iv[j].w};
            float cc[4] = {c4.x, c4.y, c4.z, c4.w};
#pragma unroll
            for (int l = 0; l < 4; ++l) {
                float c1 = cx[l] * ez - cc[l];  // conv(1-p) via conv(ones)
                float df0 = ic[l] - m0; df0 *= df0;
                float w0 = __expf(-df0 * df0);
                float df1 = ic[l] - m1; df1 *= df1;
                float w1 = __expf(-df1 * df1);
                n0 += cc[l] * pc[l] * w0;
                d0 += cc[l] * w0;
                n1 += c1 * (1.f - pc[l]) * w1;
                d1 += c1 * w1;
            }
#pragma unroll
            for (int d = 0; d < 8; ++d) win[d] = win[d + 1];
            win[8] = tn[j];
        }
    }
    double vals[4] = {(double)n0, (double)d0, (double)n1, (double)d1};
    block_reduce_store<4>(vals, pZ + 4 * lbid);
}

// single block: sum 1600 per-block partials, compute final loss
__global__ __launch_bounds__(256) void finalize_kernel(
    const double* __restrict__ pZ, float* __restrict__ out) {
    double a0 = 0, a1 = 0, a2 = 0, a3 = 0;
    for (int i = threadIdx.x; i < NBLK_Z; i += 256) {
        const double* p = &pZ[4 * i];
        a0 += p[0]; a1 += p[1]; a2 += p[2]; a3 += p[3];
    }
    __shared__ double red[4][4];
    int lane = threadIdx.x & 63;
    int wave = threadIdx.x >> 6;
    double vals[4] = {a0, a1, a2, a3};
#pragma unroll
    for (int v = 0; v < 4; ++v) {
        double x = vals[v];
#pragma unroll
        for (int off = 32; off > 0; off >>= 1) x += __shfl_down(x, off, 64);
        if (lane == 0) red[wave][v] = x;
    }
    __syncthreads();
    if (threadIdx.x == 0) {
        double acc[4];
#pragma unroll
        for (int v = 0; v < 4; ++v)
            acc[v] = red[0][v] + red[1][v] + red[2][v] + red[3][v];
        double r0 = fabs(acc[0] / (acc[1] + 1e-6));
        double r1 = fabs(acc[2] / (acc[3] + 1e-6));
        out[0] = (float)(2.0 - r0 - r1);
    }
}

extern "C" void kernel_launch(void* const* d_in, const int* in_sizes, int n_in,
                              void* d_out, int out_size, void* d_ws, size_t ws_size,
                              hipStream_t stream) {
    const float* labels = (const float*)d_in[0];
    const float* inputs = (const float*)d_in[1];
    float* out = (float*)d_out;

    // ws layout:
    //   [0)       pS : 8000*3 doubles = 192000 B
    //   [192128)  pZ : 1600*4 doubles = 51200 B  (ends 243328)
    //   [524288)  t  : 4*160^3 halves = 32,768,000 B
    double* pS = (double*)d_ws;
    double* pZ = (double*)((char*)d_ws + 192128);
    __half* t  = (__half*)((char*)d_ws + 524288);

    hipLaunchKernelGGL(conv_xy_kernel, dim3(NBLK_XY), dim3(256), 0, stream,
                       labels, inputs, t, pS);
    hipLaunchKernelGGL(conv_z_kernel, dim3(NBLK_Z), dim3(256), 0, stream,
                       t, labels, inputs, pS, pZ);
    hipLaunchKernelGGL(finalize_kernel, dim3(1), dim3(256), 0, stream, pZ, out);
}

// Round 4
// 201.407 us; speedup vs baseline: 1.0123x; 1.0038x over previous
//
#include <hip/hip_runtime.h>
#include <hip/hip_fp16.h>
#include <math.h>

#define NX   160
#define N2   25600        // 160*160
#define N3   4096000      // 160^3
#define NB   4

#define YCH  10           // y-run per conv_xy thread (R7: reg-window, no LDS)
#define NBLK_XY 1600      // 40 x4 * 16 yc * 160 z * 4 b / 256
#define XY_BLKS_PER_B 400

#define ZCH  10           // z-chunk per conv_z thread
#define NBLK_Z 1600       // 40 x4 * 160 y * 16 zc * 4 b / 256

// R6: XCD-chunked bijective swizzle (T1). HW-consecutive blocks round-robin
// XCDs; remap so each XCD owns a CONTIGUOUS logical range -> halos shared by
// logical neighbors become same-XCD L2 hits. Valid: N%8==0.
__device__ inline int xcd_swz(int bid, int nblk) {
    return (bid & 7) * (nblk >> 3) + (bid >> 3);
}

// 1D Gaussian taps exp(-d^2/50), d=-4..4 (NOT normalized, matches reference)
__device__ __constant__ float G1[9] = {
    0.72614903f, 0.83527021f, 0.92311635f, 0.98019867f, 1.0f,
    0.98019867f, 0.92311635f, 0.83527021f, 0.72614903f};

// edge sums: FULL - missing taps at low/high boundary
#define ES_FULL 7.92946852f
__device__ __constant__ float ES_M[4] = {3.46473426f, 2.48453559f, 1.56141924f,
                                         0.72614903f};
__device__ inline float edge_sum(int i) {
    float s = ES_FULL;
    if (i < 4) s -= ES_M[i];
    if (i > NX - 5) s -= ES_M[NX - 1 - i];
    return s;
}

__device__ inline float4 f4_zero() { return make_float4(0.f, 0.f, 0.f, 0.f); }
__device__ inline float4 f4_axpy(float a, float4 b, float4 c) {
    return make_float4(c.x + a * b.x, c.y + a * b.y, c.z + a * b.z, c.w + a * b.w);
}

__device__ inline float4 load_t4(const __half* p) {
    uint2 u = *(const uint2*)p;
    __half2 a = *(const __half2*)&u.x;
    __half2 b = *(const __half2*)&u.y;
    float2 fa = __half22float2(a);
    float2 fb = __half22float2(b);
    return make_float4(fa.x, fa.y, fb.x, fb.y);
}

// block = 256 threads (4 waves). Reduce NV doubles, plain store (NO atomics,
// NO fences — R4 showed per-block __threadfence+ticket costs ~600us).
template <int NV>
__device__ inline void block_reduce_store(double* vals, double* dst) {
    __shared__ double red[4][NV];
    int lane = threadIdx.x & 63;
    int wave = threadIdx.x >> 6;
#pragma unroll
    for (int v = 0; v < NV; ++v) {
        double x = vals[v];
#pragma unroll
        for (int off = 32; off > 0; off >>= 1) x += __shfl_down(x, off, 64);
        if (lane == 0) red[wave][v] = x;
    }
    __syncthreads();
    if (threadIdx.x < NV) {
        int v = threadIdx.x;
        dst[v] = red[0][v] + red[1][v] + red[2][v] + red[3][v];
    }
}

// R7: barrier-free x+y conv. Thread owns (b, z, x-float4, y-run of YCH).
// win[9] holds x-convolved rows y-4..y+4 in registers; slide along y.
// No LDS, no __syncthreads -> no phase-serialized latency chains. Fused
// per-batch partial sums -> pS (pS[3*lbid], batch = lbid/400).
__global__ __launch_bounds__(256) void conv_xy_kernel(
    const float* __restrict__ labels, const float* __restrict__ inputs,
    __half* __restrict__ t, double* __restrict__ pS) {
    int tid = threadIdx.x;
    int lbid = xcd_swz(blockIdx.x, NBLK_XY);
    int tidg = lbid * 256 + tid;
    int x4 = tidg % 40;
    int r = tidg / 40;
    int yc = r % 16;
    r /= 16;
    int z = r % NX;
    int b = r / NX;          // uniform per block (boundary at 400 blocks)

    int x0 = x4 * 4;
    int y0 = yc * YCH;
    const float* plane = labels + b * N3 + z * N2;
    const float* iplane = inputs + b * N3 + z * N2;
    __half* tplane = t + b * N3 + z * N2;

    // fill window: x-conv rows y0-4 .. y0+4
    float4 win[9];
#pragma unroll
    for (int d = 0; d < 9; ++d) {
        int gy = y0 - 4 + d;
        bool rowok = (gy >= 0) && (gy < NX);
        float w[12];
#pragma unroll
        for (int c = 0; c < 3; ++c) {
            int gx = x0 - 4 + 4 * c;
            float4 v = (rowok && gx >= 0 && gx <= NX - 4)
                           ? *(const float4*)&plane[gy * NX + gx]
                           : f4_zero();
            w[4 * c] = v.x; w[4 * c + 1] = v.y;
            w[4 * c + 2] = v.z; w[4 * c + 3] = v.w;
        }
        float4 o = f4_zero();
#pragma unroll
        for (int k = 0; k < 9; ++k) {
            float g = G1[k];
            o.x += g * w[k];     o.y += g * w[k + 1];
            o.z += g * w[k + 2]; o.w += g * w[k + 3];
        }
        win[d] = o;
    }

    double sp = 0.0, sip = 0.0, si = 0.0;
#pragma unroll 2
    for (int yo = 0; yo < YCH; ++yo) {
        int y = y0 + yo;
        // prefetch next x-conv row raw data (independent, issues early)
        int gy = y + 5;
        bool rowok = (gy < NX) && (yo < YCH - 1);
        float w[12];
#pragma unroll
        for (int c = 0; c < 3; ++c) {
            int gx = x0 - 4 + 4 * c;
            float4 v = (rowok && gx >= 0 && gx <= NX - 4)
                           ? *(const float4*)&plane[gy * NX + gx]
                           : f4_zero();
            w[4 * c] = v.x; w[4 * c + 1] = v.y;
            w[4 * c + 2] = v.z; w[4 * c + 3] = v.w;
        }
        int go = y * NX + x0;
        float4 p = *(const float4*)&plane[go];
        float4 in = *(const float4*)&iplane[go];
        // y-dot over the register window (covers load latency)
        float4 acc = f4_zero();
#pragma unroll
        for (int d = 0; d < 9; ++d) acc = f4_axpy(G1[d], win[d], acc);
        __half2 ha = __floats2half2_rn(acc.x, acc.y);
        __half2 hb = __floats2half2_rn(acc.z, acc.w);
        uint2 u;
        u.x = *(unsigned int*)&ha;
        u.y = *(unsigned int*)&hb;
        *(uint2*)&tplane[go] = u;   // 8B aligned (go%4==0)
        sp += (double)(p.x + p.y + p.z + p.w);
        sip += (double)(in.x * p.x + in.y * p.y + in.z * p.z + in.w * p.w);
        si += (double)(in.x + in.y + in.z + in.w);
        // x-conv the prefetched row, slide window
        float4 o = f4_zero();
#pragma unroll
        for (int k = 0; k < 9; ++k) {
            float g = G1[k];
            o.x += g * w[k];     o.y += g * w[k + 1];
            o.z += g * w[k + 2]; o.w += g * w[k + 3];
        }
#pragma unroll
        for (int d = 0; d < 8; ++d) win[d] = win[d + 1];
        win[8] = o;
    }
    double vals[3] = {sp, sip, si};
    block_reduce_store<3>(vals, pS + 3 * lbid);
}

// z-conv via register sliding window (float4 = 4 x-cols), t in fp16.
// reduce_S folded in: every block redundantly reduces ITS batch's 400x3
// pS partials (L2-resident, fixed order -> identical m0/m1 across blocks).
__global__ __launch_bounds__(256) void conv_z_kernel(
    const __half* __restrict__ t, const float* __restrict__ labels,
    const float* __restrict__ inputs, const double* __restrict__ pS,
    double* __restrict__ pZ) {
    int tid = threadIdx.x;
    int lbid = xcd_swz(blockIdx.x, NBLK_Z);
    int tidg = lbid * 256 + tid;  // 0 .. 409599
    int x4 = tidg % 40;           // float4 column; x = 4*x4
    int r = tidg / 40;
    int y = r % NX;
    r /= NX;
    int zc = r % 16;              // z chunk of ZCH=10
    int b = r / 16;               // uniform per block (400 blocks per batch)

    // ---- fused S reduce (replaces reduce_S_kernel) ----
    __shared__ float sM[2];
    {
        double v0 = 0, v1 = 0, v2 = 0;
        for (int i = tid; i < XY_BLKS_PER_B; i += 256) {
            const double* p = pS + 3 * (b * XY_BLKS_PER_B + i);
            v0 += p[0]; v1 += p[1]; v2 += p[2];
        }
        __shared__ double red[4][3];
        int lane = tid & 63, wave = tid >> 6;
        double vals[3] = {v0, v1, v2};
#pragma unroll
        for (int v = 0; v < 3; ++v) {
            double x = vals[v];
#pragma unroll
            for (int off = 32; off > 0; off >>= 1) x += __shfl_down(x, off, 64);
            if (lane == 0) red[wave][v] = x;
        }
        __syncthreads();
        if (tid == 0) {
            double sp = red[0][0] + red[1][0] + red[2][0] + red[3][0];
            double sip = red[0][1] + red[1][1] + red[2][1] + red[3][1];
            double si = red[0][2] + red[1][2] + red[2][2] + red[3][2];
            const double Nv = (double)N3;
            sM[0] = (float)((sip / Nv) / (sp / Nv + 1e-5));
            sM[1] = (float)(((si - sip) / Nv) / ((Nv - sp) / Nv + 1e-5));
        }
        __syncthreads();
    }
    float m0 = sM[0], m1 = sM[1];

    int x = x4 * 4;
    float ey = edge_sum(y);
    float cx[4] = {edge_sum(x) * ey, edge_sum(x + 1) * ey,
                   edge_sum(x + 2) * ey, edge_sum(x + 3) * ey};

    int z0 = zc * ZCH;
    int base = b * N3 + y * NX + x;

    float4 win[9];
#pragma unroll
    for (int d = 0; d < 9; ++d) {
        int z = z0 - 4 + d;
        win[d] = (z >= 0 && z < NX) ? load_t4(&t[base + z * N2]) : f4_zero();
    }

    float n0 = 0.f, d0 = 0.f, n1 = 0.f, d1 = 0.f;
    for (int zb = 0; zb < 5; ++zb) {
        int z = z0 + 2 * zb;
        float4 tn[2], pv[2], iv[2];
#pragma unroll
        for (int j = 0; j < 2; ++j) {
            int zl = z + j + 5;
            tn[j] = (zl < NX) ? load_t4(&t[base + zl * N2]) : f4_zero();
            int gi = base + (z + j) * N2;
            pv[j] = *(const float4*)&labels[gi];
            iv[j] = *(const float4*)&inputs[gi];
        }
#pragma unroll
        for (int j = 0; j < 2; ++j) {
            float4 c4 = f4_zero();
#pragma unroll
            for (int d = 0; d < 9; ++d) c4 = f4_axpy(G1[d], win[d], c4);
            float ez = edge_sum(z + j);
            float pc[4] = {pv[j].x, pv[j].y, pv[j].z, pv[j].w};
            float ic[4] = {iv[j].x, iv[j].y, iv[j].z, iv[j].w};
            float cc[4] = {c4.x, c4.y, c4.z, c4.w};
#pragma unroll
            for (int l = 0; l < 4; ++l) {
                float c1 = cx[l] * ez - cc[l];  // conv(1-p) via conv(ones)
                float df0 = ic[l] - m0; df0 *= df0;
                float w0 = __expf(-df0 * df0);
                float df1 = ic[l] - m1; df1 *= df1;
                float w1 = __expf(-df1 * df1);
                n0 += cc[l] * pc[l] * w0;
                d0 += cc[l] * w0;
                n1 += c1 * (1.f - pc[l]) * w1;
                d1 += c1 * w1;
            }
#pragma unroll
            for (int d = 0; d < 8; ++d) win[d] = win[d + 1];
            win[8] = tn[j];
        }
    }
    double vals[4] = {(double)n0, (double)d0, (double)n1, (double)d1};
    block_reduce_store<4>(vals, pZ + 4 * lbid);
}

// single block: sum 1600 per-block partials, compute final loss
__global__ __launch_bounds__(256) void finalize_kernel(
    const double* __restrict__ pZ, float* __restrict__ out) {
    double a0 = 0, a1 = 0, a2 = 0, a3 = 0;
    for (int i = threadIdx.x; i < NBLK_Z; i += 256) {
        const double* p = &pZ[4 * i];
        a0 += p[0]; a1 += p[1]; a2 += p[2]; a3 += p[3];
    }
    __shared__ double red[4][4];
    int lane = threadIdx.x & 63;
    int wave = threadIdx.x >> 6;
    double vals[4] = {a0, a1, a2, a3};
#pragma unroll
    for (int v = 0; v < 4; ++v) {
        double x = vals[v];
#pragma unroll
        for (int off = 32; off > 0; off >>= 1) x += __shfl_down(x, off, 64);
        if (lane == 0) red[wave][v] = x;
    }
    __syncthreads();
    if (threadIdx.x == 0) {
        double acc[4];
#pragma unroll
        for (int v = 0; v < 4; ++v)
            acc[v] = red[0][v] + red[1][v] + red[2][v] + red[3][v];
        double r0 = fabs(acc[0] / (acc[1] + 1e-6));
        double r1 = fabs(acc[2] / (acc[3] + 1e-6));
        out[0] = (float)(2.0 - r0 - r1);
    }
}

extern "C" void kernel_launch(void* const* d_in, const int* in_sizes, int n_in,
                              void* d_out, int out_size, void* d_ws, size_t ws_size,
                              hipStream_t stream) {
    const float* labels = (const float*)d_in[0];
    const float* inputs = (const float*)d_in[1];
    float* out = (float*)d_out;

    // ws layout:
    //   [0)       pS : 1600*3 doubles = 38400 B
    //   [192128)  pZ : 1600*4 doubles = 51200 B  (ends 243328)
    //   [524288)  t  : 4*160^3 halves = 32,768,000 B
    double* pS = (double*)d_ws;
    double* pZ = (double*)((char*)d_ws + 192128);
    __half* t  = (__half*)((char*)d_ws + 524288);

    hipLaunchKernelGGL(conv_xy_kernel, dim3(NBLK_XY), dim3(256), 0, stream,
                       labels, inputs, t, pS);
    hipLaunchKernelGGL(conv_z_kernel, dim3(NBLK_Z), dim3(256), 0, stream,
                       t, labels, inputs, pS, pZ);
    hipLaunchKernelGGL(finalize_kernel, dim3(1), dim3(256), 0, stream, pZ, out);
}

// Round 5
// 196.488 us; speedup vs baseline: 1.0377x; 1.0250x over previous
//
#include <hip/hip_runtime.h>
#include <hip/hip_fp16.h>
#include <math.h>

#define NX   160
#define N2   25600        // 160*160
#define N3   4096000      // 160^3
#define NB   4

#define YCH  10           // y-run per conv_xy thread (reg-window, no LDS)
#define NBLK_XY 1600      // 8 xcd * 200 units
#define ZSLAB 20          // z-planes owned per XCD (160/8)

#define ZCH  20           // z-run per conv_z thread (= one slab)
#define NBLK_Z 800        // 8 xcd * 100 units

// 1D Gaussian taps exp(-d^2/50), d=-4..4 (NOT normalized, matches reference)
__device__ __constant__ float G1[9] = {
    0.72614903f, 0.83527021f, 0.92311635f, 0.98019867f, 1.0f,
    0.98019867f, 0.92311635f, 0.83527021f, 0.72614903f};

// edge sums: FULL - missing taps at low/high boundary
#define ES_FULL 7.92946852f
__device__ __constant__ float ES_M[4] = {3.46473426f, 2.48453559f, 1.56141924f,
                                         0.72614903f};
__device__ inline float edge_sum(int i) {
    float s = ES_FULL;
    if (i < 4) s -= ES_M[i];
    if (i > NX - 5) s -= ES_M[NX - 1 - i];
    return s;
}

__device__ inline float4 f4_zero() { return make_float4(0.f, 0.f, 0.f, 0.f); }
__device__ inline float4 f4_axpy(float a, float4 b, float4 c) {
    return make_float4(c.x + a * b.x, c.y + a * b.y, c.z + a * b.z, c.w + a * b.w);
}

__device__ inline float4 load_t4(const __half* p) {
    uint2 u = *(const uint2*)p;
    __half2 a = *(const __half2*)&u.x;
    __half2 b = *(const __half2*)&u.y;
    float2 fa = __half22float2(a);
    float2 fb = __half22float2(b);
    return make_float4(fa.x, fa.y, fb.x, fb.y);
}

// block = 256 threads (4 waves). Reduce NV doubles, plain store (NO atomics,
// NO fences — R4 showed per-block __threadfence+ticket costs ~600us).
template <int NV>
__device__ inline void block_reduce_store(double* vals, double* dst) {
    __shared__ double red[4][NV];
    int lane = threadIdx.x & 63;
    int wave = threadIdx.x >> 6;
#pragma unroll
    for (int v = 0; v < NV; ++v) {
        double x = vals[v];
#pragma unroll
        for (int off = 32; off > 0; off >>= 1) x += __shfl_down(x, off, 64);
        if (lane == 0) red[wave][v] = x;
    }
    __syncthreads();
    if (threadIdx.x < NV) {
        int v = threadIdx.x;
        dst[v] = red[0][v] + red[1][v] + red[2][v] + red[3][v];
    }
}

// R8: XCD-slab mapping. Physical block p -> xcd = p&7 (HW round-robin), and
// XCD x owns z in [20x, 20x+20). Halo/overlap re-reads stay in that XCD's L2,
// and conv_z later re-reads the t-slab its own XCD wrote.
// Body = R7 barrier-free reg-window x+y conv (known-good).
// pS layout: pS[3*p]; batch of p = (p>>3)/50 -> batch-b blocks are the
// CONTIGUOUS physical range [400b, 400b+400).
__global__ __launch_bounds__(256) void conv_xy_kernel(
    const float* __restrict__ labels, const float* __restrict__ inputs,
    __half* __restrict__ t, double* __restrict__ pS) {
    int tid = threadIdx.x;
    int xcd = blockIdx.x & 7;
    int v   = blockIdx.x >> 3;        // 0..199, y-major -> z -> b within XCD
    int idx = v * 256 + tid;          // 0..51199 within XCD
    int x4  = idx % 40;
    int rest = idx / 40;              // 0..1279
    int yc  = rest % 16;
    int zb  = rest / 16;              // 0..79
    int z   = (zb % ZSLAB) + ZSLAB * xcd;
    int b   = zb / ZSLAB;             // uniform per block (12800 % 256 == 0)

    int x0 = x4 * 4;
    int y0 = yc * YCH;
    const float* plane = labels + b * N3 + z * N2;
    const float* iplane = inputs + b * N3 + z * N2;
    __half* tplane = t + b * N3 + z * N2;

    // fill window: x-conv rows y0-4 .. y0+4
    float4 win[9];
#pragma unroll
    for (int d = 0; d < 9; ++d) {
        int gy = y0 - 4 + d;
        bool rowok = (gy >= 0) && (gy < NX);
        float w[12];
#pragma unroll
        for (int c = 0; c < 3; ++c) {
            int gx = x0 - 4 + 4 * c;
            float4 vv = (rowok && gx >= 0 && gx <= NX - 4)
                            ? *(const float4*)&plane[gy * NX + gx]
                            : f4_zero();
            w[4 * c] = vv.x; w[4 * c + 1] = vv.y;
            w[4 * c + 2] = vv.z; w[4 * c + 3] = vv.w;
        }
        float4 o = f4_zero();
#pragma unroll
        for (int k = 0; k < 9; ++k) {
            float g = G1[k];
            o.x += g * w[k];     o.y += g * w[k + 1];
            o.z += g * w[k + 2]; o.w += g * w[k + 3];
        }
        win[d] = o;
    }

    double sp = 0.0, sip = 0.0, si = 0.0;
#pragma unroll 2
    for (int yo = 0; yo < YCH; ++yo) {
        int y = y0 + yo;
        // prefetch next x-conv row raw data (independent, issues early)
        int gy = y + 5;
        bool rowok = (gy < NX) && (yo < YCH - 1);
        float w[12];
#pragma unroll
        for (int c = 0; c < 3; ++c) {
            int gx = x0 - 4 + 4 * c;
            float4 vv = (rowok && gx >= 0 && gx <= NX - 4)
                            ? *(const float4*)&plane[gy * NX + gx]
                            : f4_zero();
            w[4 * c] = vv.x; w[4 * c + 1] = vv.y;
            w[4 * c + 2] = vv.z; w[4 * c + 3] = vv.w;
        }
        int go = y * NX + x0;
        float4 p = *(const float4*)&plane[go];
        float4 in = *(const float4*)&iplane[go];
        // y-dot over the register window (covers load latency)
        float4 acc = f4_zero();
#pragma unroll
        for (int d = 0; d < 9; ++d) acc = f4_axpy(G1[d], win[d], acc);
        __half2 ha = __floats2half2_rn(acc.x, acc.y);
        __half2 hb = __floats2half2_rn(acc.z, acc.w);
        uint2 u;
        u.x = *(unsigned int*)&ha;
        u.y = *(unsigned int*)&hb;
        *(uint2*)&tplane[go] = u;   // 8B aligned (go%4==0)
        sp += (double)(p.x + p.y + p.z + p.w);
        sip += (double)(in.x * p.x + in.y * p.y + in.z * p.z + in.w * p.w);
        si += (double)(in.x + in.y + in.z + in.w);
        // x-conv the prefetched row, slide window
        float4 o = f4_zero();
#pragma unroll
        for (int k = 0; k < 9; ++k) {
            float g = G1[k];
            o.x += g * w[k];     o.y += g * w[k + 1];
            o.z += g * w[k + 2]; o.w += g * w[k + 3];
        }
#pragma unroll
        for (int d = 0; d < 8; ++d) win[d] = win[d + 1];
        win[8] = o;
    }
    double vals[3] = {sp, sip, si};
    block_reduce_store<3>(vals, pS + 3 * blockIdx.x);
}

// R8: z-conv, slab-aligned: block's threads all run z over THEIR XCD's slab
// [20*xcd, 20*xcd+20), so 20/28 t-planes read were written by this XCD
// (dirty-L2 candidates); 8 halo planes come from neighbors. ZCH=20 restores
// R0's 1.4x t amplification (R5's ZCH=10 was 1.9x). Body = R0 4-deep batch.
// Fused S reduce: every block reduces ITS batch's contiguous pS[400b..400b+400)
// in identical order -> identical m0/m1 across blocks.
__global__ __launch_bounds__(256) void conv_z_kernel(
    const __half* __restrict__ t, const float* __restrict__ labels,
    const float* __restrict__ inputs, const double* __restrict__ pS,
    double* __restrict__ pZ) {
    int tid = threadIdx.x;
    int xcd = blockIdx.x & 7;
    int c   = blockIdx.x >> 3;    // 0..99
    int idx = c * 256 + tid;      // 0..25599 within XCD
    int x4 = idx % 40;            // float4 column; x = 4*x4
    int rest = idx / 40;          // 0..639
    int y = rest % NX;
    int b = rest / NX;            // uniform per block (6400 % 256 == 0)
    int z0 = ZSLAB * xcd;

    // ---- fused S reduce (batch b's blocks are pS[400b .. 400b+400)) ----
    __shared__ float sM[2];
    {
        double v0 = 0, v1 = 0, v2 = 0;
        for (int i = tid; i < 400; i += 256) {
            const double* p = pS + 3 * (400 * b + i);
            v0 += p[0]; v1 += p[1]; v2 += p[2];
        }
        __shared__ double red[4][3];
        int lane = tid & 63, wave = tid >> 6;
        double vals[3] = {v0, v1, v2};
#pragma unroll
        for (int v = 0; v < 3; ++v) {
            double x = vals[v];
#pragma unroll
            for (int off = 32; off > 0; off >>= 1) x += __shfl_down(x, off, 64);
            if (lane == 0) red[wave][v] = x;
        }
        __syncthreads();
        if (tid == 0) {
            double sp = red[0][0] + red[1][0] + red[2][0] + red[3][0];
            double sip = red[0][1] + red[1][1] + red[2][1] + red[3][1];
            double si = red[0][2] + red[1][2] + red[2][2] + red[3][2];
            const double Nv = (double)N3;
            sM[0] = (float)((sip / Nv) / (sp / Nv + 1e-5));
            sM[1] = (float)(((si - sip) / Nv) / ((Nv - sp) / Nv + 1e-5));
        }
        __syncthreads();
    }
    float m0 = sM[0], m1 = sM[1];

    int x = x4 * 4;
    float ey = edge_sum(y);
    float cx[4] = {edge_sum(x) * ey, edge_sum(x + 1) * ey,
                   edge_sum(x + 2) * ey, edge_sum(x + 3) * ey};

    int base = b * N3 + y * NX + x;

    float4 win[9];
#pragma unroll
    for (int d = 0; d < 9; ++d) {
        int z = z0 - 4 + d;
        win[d] = (z >= 0 && z < NX) ? load_t4(&t[base + z * N2]) : f4_zero();
    }

    float n0 = 0.f, d0 = 0.f, n1 = 0.f, d1 = 0.f;
    for (int zb5 = 0; zb5 < 5; ++zb5) {
        int z = z0 + 4 * zb5;
        float4 tn[4], pv[4], iv[4];
#pragma unroll
        for (int j = 0; j < 4; ++j) {
            int zl = z + j + 5;
            tn[j] = (zl < NX) ? load_t4(&t[base + zl * N2]) : f4_zero();
            int gi = base + (z + j) * N2;
            pv[j] = *(const float4*)&labels[gi];
            iv[j] = *(const float4*)&inputs[gi];
        }
#pragma unroll
        for (int j = 0; j < 4; ++j) {
            float4 c4 = f4_zero();
#pragma unroll
            for (int d = 0; d < 9; ++d) c4 = f4_axpy(G1[d], win[d], c4);
            float ez = edge_sum(z + j);
            float pc[4] = {pv[j].x, pv[j].y, pv[j].z, pv[j].w};
            float ic[4] = {iv[j].x, iv[j].y, iv[j].z, iv[j].w};
            float cc[4] = {c4.x, c4.y, c4.z, c4.w};
#pragma unroll
            for (int l = 0; l < 4; ++l) {
                float c1 = cx[l] * ez - cc[l];  // conv(1-p) via conv(ones)
                float df0 = ic[l] - m0; df0 *= df0;
                float w0 = __expf(-df0 * df0);
                float df1 = ic[l] - m1; df1 *= df1;
                float w1 = __expf(-df1 * df1);
                n0 += cc[l] * pc[l] * w0;
                d0 += cc[l] * w0;
                n1 += c1 * (1.f - pc[l]) * w1;
                d1 += c1 * w1;
            }
#pragma unroll
            for (int d = 0; d < 8; ++d) win[d] = win[d + 1];
            win[8] = tn[j];
        }
    }
    double vals[4] = {(double)n0, (double)d0, (double)n1, (double)d1};
    block_reduce_store<4>(vals, pZ + 4 * blockIdx.x);
}

// single block: sum 800 per-block partials, compute final loss
__global__ __launch_bounds__(256) void finalize_kernel(
    const double* __restrict__ pZ, float* __restrict__ out) {
    double a0 = 0, a1 = 0, a2 = 0, a3 = 0;
    for (int i = threadIdx.x; i < NBLK_Z; i += 256) {
        const double* p = &pZ[4 * i];
        a0 += p[0]; a1 += p[1]; a2 += p[2]; a3 += p[3];
    }
    __shared__ double red[4][4];
    int lane = threadIdx.x & 63;
    int wave = threadIdx.x >> 6;
    double vals[4] = {a0, a1, a2, a3};
#pragma unroll
    for (int v = 0; v < 4; ++v) {
        double x = vals[v];
#pragma unroll
        for (int off = 32; off > 0; off >>= 1) x += __shfl_down(x, off, 64);
        if (lane == 0) red[wave][v] = x;
    }
    __syncthreads();
    if (threadIdx.x == 0) {
        double acc[4];
#pragma unroll
        for (int v = 0; v < 4; ++v)
            acc[v] = red[0][v] + red[1][v] + red[2][v] + red[3][v];
        double r0 = fabs(acc[0] / (acc[1] + 1e-6));
        double r1 = fabs(acc[2] / (acc[3] + 1e-6));
        out[0] = (float)(2.0 - r0 - r1);
    }
}

extern "C" void kernel_launch(void* const* d_in, const int* in_sizes, int n_in,
                              void* d_out, int out_size, void* d_ws, size_t ws_size,
                              hipStream_t stream) {
    const float* labels = (const float*)d_in[0];
    const float* inputs = (const float*)d_in[1];
    float* out = (float*)d_out;

    // ws layout:
    //   [0)       pS : 1600*3 doubles = 38400 B
    //   [192128)  pZ : 800*4 doubles = 25600 B  (ends 217728)
    //   [524288)  t  : 4*160^3 halves = 32,768,000 B
    double* pS = (double*)d_ws;
    double* pZ = (double*)((char*)d_ws + 192128);
    __half* t  = (__half*)((char*)d_ws + 524288);

    hipLaunchKernelGGL(conv_xy_kernel, dim3(NBLK_XY), dim3(256), 0, stream,
                       labels, inputs, t, pS);
    hipLaunchKernelGGL(conv_z_kernel, dim3(NBLK_Z), dim3(256), 0, stream,
                       t, labels, inputs, pS, pZ);
    hipLaunchKernelGGL(finalize_kernel, dim3(1), dim3(256), 0, stream, pZ, out);
}